// Round 1
// baseline (545.438 us; speedup 1.0000x reference)
//
#include <hip/hip_runtime.h>
#include <hip/hip_bf16.h>

// Problem constants (B=8, L=8192, C=256, PE=96, R=90, UP=4, OUT=256)
#define M_TOTAL 65536   // B*L
#define N_TOTAL 1024    // OUT*UP
#define K_TOTAL 448     // C + 2*PE
#define R_PE    90

typedef __bf16 bf16x8 __attribute__((ext_vector_type(8)));
typedef __bf16 bf16x4 __attribute__((ext_vector_type(4)));
typedef float  floatx4 __attribute__((ext_vector_type(4)));

// ---------------------------------------------------------------------------
// async global->LDS, 16B per lane. LDS dest = wave-uniform base + lane*16.
// ---------------------------------------------------------------------------
__device__ __forceinline__ void g2lds16(const void* g, void* l) {
    __builtin_amdgcn_global_load_lds(
        (const __attribute__((address_space(1))) void*)g,
        (__attribute__((address_space(3))) void*)l,
        16, 0, 0);
}

// ---------------------------------------------------------------------------
// Stage 1: x_pe[m, 0:448] = [bf16(x[m]), sin(LFF(pc[m])), constPE(pc[m])]
// One row per 256-thread iteration:
//   lanes   0..63  : float4 copy of x (256 f32 -> bf16)
//   lanes  64..159 : lpe[d] = sin(pc . lff_w[d] + lff_b[d])
//   lanes 160..255 : cpe[d] = bilinear PE, sum over 3 channels / sqrt(3)
// ---------------------------------------------------------------------------
__global__ __launch_bounds__(256) void build_xpe(
    const float* __restrict__ X,      // [65536, 256]
    const float* __restrict__ pc,     // [65536, 3]
    const float* __restrict__ lff_w,  // [96, 3]
    const float* __restrict__ lff_b,  // [96]
    const float* __restrict__ cpe_t,  // [3, 96, 90]
    __bf16* __restrict__ xpe)         // [65536, 448]
{
    const int tid = threadIdx.x;
    for (int m = blockIdx.x; m < M_TOTAL; m += gridDim.x) {
        __bf16* row = xpe + (size_t)m * K_TOTAL;
        if (tid < 64) {
            float4 v = ((const float4*)(X + (size_t)m * 256))[tid];
            bf16x4 o = { (__bf16)v.x, (__bf16)v.y, (__bf16)v.z, (__bf16)v.w };
            *(bf16x4*)(row + tid * 4) = o;
        } else {
            const float p0 = pc[m * 3 + 0];
            const float p1 = pc[m * 3 + 1];
            const float p2 = pc[m * 3 + 2];
            if (tid < 160) {
                const int d = tid - 64;
                float a = p0 * lff_w[d * 3 + 0] + p1 * lff_w[d * 3 + 1]
                        + p2 * lff_w[d * 3 + 2] + lff_b[d];
                row[256 + d] = (__bf16)__sinf(a) == (__bf16)0.f && false
                             ? (__bf16)0.f : (__bf16)sinf(a);
            } else {
                const int d = tid - 160;
                float p[3] = { p0, p1, p2 };
                float acc = 0.f;
                #pragma unroll
                for (int c = 0; c < 3; ++c) {
                    // ix = ((p+1)*R - 1) * 0.5
                    float ix = (p[c] + 1.f) * 45.f - 0.5f;
                    float fl = floorf(ix);
                    float w  = ix - fl;
                    int i0 = (int)fl;
                    const float* tab = cpe_t + ((size_t)c * 96 + d) * R_PE;
                    float v0 = (i0 >= 0 && i0 < R_PE)         ? tab[i0]     : 0.f;
                    float v1 = (i0 + 1 >= 0 && i0 + 1 < R_PE) ? tab[i0 + 1] : 0.f;
                    acc += v0 + (v1 - v0) * w;   // v0*(1-w) + v1*w
                }
                row[352 + d] = (__bf16)(acc * 0.57735026918962576f); // 1/sqrt(3)
            }
        }
    }
}

// ---------------------------------------------------------------------------
// sub_w [1024,448] f32 -> bf16 (already B^T layout: N-major, K-contiguous)
// ---------------------------------------------------------------------------
__global__ __launch_bounds__(256) void convert_w(
    const float* __restrict__ w, __bf16* __restrict__ wb)
{
    int i = (blockIdx.x * 256 + threadIdx.x) * 4;
    if (i < N_TOTAL * K_TOTAL) {
        float4 v = *(const float4*)(w + i);
        bf16x4 o = { (__bf16)v.x, (__bf16)v.y, (__bf16)v.z, (__bf16)v.w };
        *(bf16x4*)(wb + i) = o;
    }
}

// ---------------------------------------------------------------------------
// pc_up: repeat_interleave(pc, 4, axis=1). out2[m*12 + u*3 + j] = pc[m*3 + j]
// ---------------------------------------------------------------------------
__global__ __launch_bounds__(256) void pc_up_kernel(
    const float* __restrict__ pc, float* __restrict__ out2)
{
    int e = blockIdx.x * 256 + threadIdx.x;
    if (e < M_TOTAL * 12) {
        int m = e / 12;
        int j = e % 3;          // (m*12) % 3 == 0, so e%3 == jj
        out2[e] = pc[m * 3 + j];
    }
}

// ---------------------------------------------------------------------------
// GEMM: C[m,n] = sum_k xpe[m,k] * sub_w[n,k], fused subpixel epilogue.
// 128x128 tile, BK=64, 4 waves, each wave 64x64 = 4x4 tiles of 16x16x32 bf16.
// Epilogue: y = acc/sqrt(448) + bias[n]; lrelu(y)*sqrt2; out = (x + that)/sqrt2
//   n = u*256 + o;  out[(m*4+u)*256 + o] = x[m,o]*(1/sqrt2) + lrelu(y)  (sqrt2/sqrt2=1)
// ---------------------------------------------------------------------------
__global__ __launch_bounds__(256) void gemm_kernel(
    const __bf16* __restrict__ A,    // [65536, 448] bf16 (x_pe)
    const __bf16* __restrict__ Bw,   // [1024, 448] bf16 (sub_w^T-major)
    const float* __restrict__ bias,  // [1024]
    const float* __restrict__ X,     // [65536, 256] f32 residual
    float* __restrict__ out)         // x_up part of d_out
{
    __shared__ __bf16 As[128 * 64];  // 16 KB
    __shared__ __bf16 Bs[128 * 64];  // 16 KB

    const int tid  = threadIdx.x;
    const int wave = tid >> 6;
    const int lane = tid & 63;
    const int quad = lane >> 4;
    const int l16  = lane & 15;
    const int wm   = (wave >> 1) * 64;   // wave row origin in tile
    const int wn   = (wave & 1) * 64;    // wave col origin in tile

    // XCD-aware swizzle: all 8 N-blocks of one M-tile land on the same XCD,
    // dispatched within a 64-block window (A-tile and residual-x L2 reuse).
    const unsigned bx = blockIdx.x;                 // [0, 4096)
    const int bm = (int)(((bx & 7u) * 64u + (bx >> 6)) * 128u);  // m0: 512 tiles
    const int bn = (int)(((bx >> 3) & 7u) * 128u);               // n0: 8 tiles

    floatx4 acc[4][4];
    #pragma unroll
    for (int i = 0; i < 4; ++i)
        #pragma unroll
        for (int j = 0; j < 4; ++j)
            acc[i][j] = (floatx4){0.f, 0.f, 0.f, 0.f};

    for (int kt = 0; kt < K_TOTAL; kt += 64) {
        __syncthreads();   // previous iter's LDS reads done
        #pragma unroll
        for (int s = 0; s < 4; ++s) {
            const int idx = s * 256 + tid;        // 16B chunk id, [0,1024)
            const int r   = idx >> 3;             // tile row
            const int c   = (idx & 7) * 8;        // k offset within BK
            // wave-uniform LDS base; HW adds lane*16
            __bf16* ldsA = As + (size_t)(s * 256 + wave * 64) * 8;
            __bf16* ldsB = Bs + (size_t)(s * 256 + wave * 64) * 8;
            g2lds16(A  + (size_t)(bm + r) * K_TOTAL + kt + c, ldsA);
            g2lds16(Bw + (size_t)(bn + r) * K_TOTAL + kt + c, ldsB);
        }
        __syncthreads();   // drains vmcnt (compiler-inserted before s_barrier)

        #pragma unroll
        for (int s = 0; s < 2; ++s) {
            bf16x8 af[4], bf[4];
            #pragma unroll
            for (int i = 0; i < 4; ++i)
                af[i] = *(const bf16x8*)(As + (wm + i * 16 + l16) * 64 + s * 32 + quad * 8);
            #pragma unroll
            for (int j = 0; j < 4; ++j)
                bf[j] = *(const bf16x8*)(Bs + (wn + j * 16 + l16) * 64 + s * 32 + quad * 8);
            #pragma unroll
            for (int i = 0; i < 4; ++i)
                #pragma unroll
                for (int j = 0; j < 4; ++j)
                    acc[i][j] = __builtin_amdgcn_mfma_f32_16x16x32_bf16(
                        af[i], bf[j], acc[i][j], 0, 0, 0);
        }
    }

    // ---- fused epilogue ----
    const float gain = 0.047245559126153576f;     // 1/sqrt(448)
    const float inv_sqrt2 = 0.70710678118654752f;
    #pragma unroll
    for (int i = 0; i < 4; ++i) {
        #pragma unroll
        for (int j = 0; j < 4; ++j) {
            const int n = bn + wn + j * 16 + l16;
            const float bs = bias[n];
            const int o = n & 255;
            const int u = n >> 8;
            #pragma unroll
            for (int r = 0; r < 4; ++r) {
                const int m = bm + wm + i * 16 + quad * 4 + r;
                float y = acc[i][j][r] * gain + bs;
                float act = (y >= 0.f) ? y : 0.2f * y;   // lrelu*sqrt2 later /sqrt2 == 1
                float res = X[(size_t)m * 256 + o];
                out[((size_t)(m * 4 + u)) * 256 + o] = fmaf(res, inv_sqrt2, act);
            }
        }
    }
}

// ---------------------------------------------------------------------------
extern "C" void kernel_launch(void* const* d_in, const int* in_sizes, int n_in,
                              void* d_out, int out_size, void* d_ws, size_t ws_size,
                              hipStream_t stream) {
    const float* X      = (const float*)d_in[0];  // [8,8192,256]
    const float* pc     = (const float*)d_in[1];  // [8,8192,3]
    const float* lff_w  = (const float*)d_in[2];  // [96,3]
    const float* lff_b  = (const float*)d_in[3];  // [96]
    const float* cpe    = (const float*)d_in[4];  // [3,96,90]
    const float* sub_w  = (const float*)d_in[5];  // [1024,448]
    const float* sub_b  = (const float*)d_in[6];  // [1024]

    float* out    = (float*)d_out;                       // x_up: 67108864 floats
    float* out_pc = out + (size_t)M_TOTAL * 4 * 256;     // pc_up: 786432 floats

    // workspace: x_pe bf16 [65536,448] then sub_w bf16 [1024,448]
    __bf16* xpe = (__bf16*)d_ws;
    __bf16* wb  = (__bf16*)((char*)d_ws + (size_t)M_TOTAL * K_TOTAL * 2);

    convert_w  <<<448,  256, 0, stream>>>(sub_w, wb);
    pc_up_kernel<<<3072, 256, 0, stream>>>(pc, out_pc);
    build_xpe  <<<4096, 256, 0, stream>>>(X, pc, lff_w, lff_b, cpe, xpe);
    gemm_kernel<<<4096, 256, 0, stream>>>(xpe, wb, sub_b, X, out);
}